// Round 7
// baseline (569.411 us; speedup 1.0000x reference)
//
#include <hip/hip_runtime.h>

typedef unsigned int uint;
typedef unsigned short ushort;

typedef short bf16x8 __attribute__((ext_vector_type(8)));
typedef float f32x4 __attribute__((ext_vector_type(4)));

__device__ inline ushort f2bf(float f) {
  uint u = __float_as_uint(f);
  u += 0x7fffu + ((u >> 16) & 1u);   // round-to-nearest-even
  return (ushort)(u >> 16);
}
__device__ inline float bf2f(ushort h) { return __uint_as_float((uint)h << 16); }
__device__ inline float bf_lo(uint u) { return __uint_as_float(u << 16); }
__device__ inline float bf_hi(uint u) { return __uint_as_float(u & 0xffff0000u); }
__device__ inline void split2(float v, ushort& h, ushort& l) {
  ushort hh = f2bf(v);
  h = hh;
  l = f2bf(v - bf2f(hh));    // exact residual, captures ~8 more mantissa bits
}

// ---------------- CSR construction ----------------

__global__ __launch_bounds__(256) void hist_kernel(const int* __restrict__ dst,
                                                   int* __restrict__ deg, int nE) {
  int i = blockIdx.x * 256 + threadIdx.x;
  int stride = gridDim.x * 256;
  for (; i < nE; i += stride) atomicAdd(&deg[dst[i]], 1);
}

__global__ __launch_bounds__(256) void scan1(const int* __restrict__ deg,
                                             int* __restrict__ row_off,
                                             int* __restrict__ blocksums, int n) {
  __shared__ int s[256];
  int t = threadIdx.x, i = blockIdx.x * 256 + t;
  int v = (i < n) ? deg[i] : 0;
  s[t] = v;
  __syncthreads();
  for (int off = 1; off < 256; off <<= 1) {
    int x = (t >= off) ? s[t - off] : 0;
    __syncthreads();
    s[t] += x;
    __syncthreads();
  }
  if (i < n) row_off[i] = s[t] - v;        // local exclusive scan
  if (t == 255) blocksums[blockIdx.x] = s[t];
}

__global__ __launch_bounds__(512) void scan2(int* __restrict__ blocksums, int nb,
                                             int* __restrict__ total_out) {
  __shared__ int s[512];
  int t = threadIdx.x;
  int v = (t < nb) ? blocksums[t] : 0;
  s[t] = v;
  __syncthreads();
  for (int off = 1; off < 512; off <<= 1) {
    int x = (t >= off) ? s[t - off] : 0;
    __syncthreads();
    s[t] += x;
    __syncthreads();
  }
  if (t < nb) blocksums[t] = s[t] - v;     // exclusive block offsets
  if (t == 511) *total_out = s[511];       // row_off[N] = nE
}

__global__ __launch_bounds__(256) void scan3_dinv(int* __restrict__ row_off,
                                                  const int* __restrict__ blockoff,
                                                  const int* __restrict__ deg,
                                                  float* __restrict__ dinv, int n) {
  int i = blockIdx.x * 256 + threadIdx.x;
  if (i < n) {
    row_off[i] += blockoff[i >> 8];
    dinv[i] = rsqrtf((float)deg[i] + 1.0f);
  }
}

// Windowed counting-sort scatter (4 passes): write span per pass is contiguous
// ~1.6 MB -> L2-resident, lines fill fully before eviction.
__global__ __launch_bounds__(256) void scatter_kernel(const int* __restrict__ src,
                                                      const int* __restrict__ dst,
                                                      const int* __restrict__ row_off,
                                                      int* __restrict__ cursor,
                                                      int* __restrict__ edge_src, int nE,
                                                      int lo, int hi) {
  int i = blockIdx.x * 256 + threadIdx.x;
  int stride = gridDim.x * 256;
  for (; i < nE; i += stride) {
    int d = dst[i];
    if (d >= lo && d < hi) {
      int pos = row_off[d] + atomicAdd(&cursor[d], 1);
      edge_src[pos] = src[i];
    }
  }
}

// ---------------- input splitting (fp32 -> bf16 hi/lo pair) ----------------

__global__ __launch_bounds__(256) void split_x_kernel(const float* __restrict__ X,
                                                      ushort* __restrict__ Xhi,
                                                      ushort* __restrict__ Xlo, int n4) {
  int i = blockIdx.x * 256 + threadIdx.x;
  int stride = gridDim.x * 256;
  for (; i < n4; i += stride) {
    float4 v = *(const float4*)(X + (size_t)i * 4);
    ushort4 h, l;
    split2(v.x, h.x, l.x);
    split2(v.y, h.y, l.y);
    split2(v.z, h.z, l.z);
    split2(v.w, h.w, l.w);
    *(ushort4*)(Xhi + (size_t)i * 4) = h;
    *(ushort4*)(Xlo + (size_t)i * 4) = l;
  }
}

// W [K=128][C] row-major -> transposed hi/lo [C][128]
__global__ __launch_bounds__(256) void split_wT_kernel(const float* __restrict__ W,
                                                       ushort* __restrict__ WThi,
                                                       ushort* __restrict__ WTlo, int C) {
  int idx = blockIdx.x * 256 + threadIdx.x;
  if (idx < 128 * C) {
    int k = idx / C, c = idx % C;
    ushort h, l;
    split2(W[idx], h, l);
    WThi[c * 128 + k] = h;
    WTlo[c * 128 + k] = l;
  }
}

// ---------------- MFMA GEMM: Y[N][COLS] = X[N][128] @ W[128][COLS] ----------------
// Inputs as bf16 hi/lo pairs; product = hi*hi + hi*lo + lo*hi (3 MFMA passes,
// ~2^-18 rel error). 256 thr = 4 waves; block tile 128 rows; wave tile 32 rows.
// A-frags loaded straight to regs (each element used once); B from L2-resident
// transposed W (16B/lane loads). No LDS.
template <int COLS, bool OUT_BF16>
__global__ __launch_bounds__(256) void gemm_mfma(const ushort* __restrict__ Ahi,
                                                 const ushort* __restrict__ Alo,
                                                 const ushort* __restrict__ WThi,
                                                 const ushort* __restrict__ WTlo,
                                                 const float* __restrict__ bias,
                                                 void* __restrict__ Yv, int nrows) {
  constexpr int NCF = COLS / 16;  // col fragments: 8 or 4
  int tid = threadIdx.x;
  int w = tid >> 6;
  int lane = tid & 63;
  int lrow = lane & 15;
  int k0 = (lane >> 4) * 8;
  long row0 = (long)blockIdx.x * 128 + w * 32;

  f32x4 acc[2][NCF];
#pragma unroll
  for (int rf = 0; rf < 2; ++rf)
#pragma unroll
    for (int cf = 0; cf < NCF; ++cf) acc[rf][cf] = (f32x4){0.f, 0.f, 0.f, 0.f};

  const bf16x8 zero8 = {0, 0, 0, 0, 0, 0, 0, 0};
#pragma unroll
  for (int ks = 0; ks < 4; ++ks) {
    int kk = ks * 32 + k0;
    bf16x8 a_hi[2], a_lo[2];
#pragma unroll
    for (int rf = 0; rf < 2; ++rf) {
      long r = row0 + rf * 16 + lrow;
      bool ok = r < nrows;
      a_hi[rf] = ok ? *(const bf16x8*)(Ahi + r * 128 + kk) : zero8;
      a_lo[rf] = ok ? *(const bf16x8*)(Alo + r * 128 + kk) : zero8;
    }
    bf16x8 b_hi[NCF], b_lo[NCF];
#pragma unroll
    for (int cf = 0; cf < NCF; ++cf) {
      int c = cf * 16 + lrow;
      b_hi[cf] = *(const bf16x8*)(WThi + c * 128 + kk);
      b_lo[cf] = *(const bf16x8*)(WTlo + c * 128 + kk);
    }
#pragma unroll
    for (int rf = 0; rf < 2; ++rf)
#pragma unroll
      for (int cf = 0; cf < NCF; ++cf) {
        acc[rf][cf] = __builtin_amdgcn_mfma_f32_16x16x32_bf16(a_hi[rf], b_hi[cf], acc[rf][cf], 0, 0, 0);
        acc[rf][cf] = __builtin_amdgcn_mfma_f32_16x16x32_bf16(a_hi[rf], b_lo[cf], acc[rf][cf], 0, 0, 0);
        acc[rf][cf] = __builtin_amdgcn_mfma_f32_16x16x32_bf16(a_lo[rf], b_hi[cf], acc[rf][cf], 0, 0, 0);
      }
  }

  // epilogue: C/D layout col=lane&15, row=(lane>>4)*4+r  [m89-verified]
  int rbase = (lane >> 4) * 4;
#pragma unroll
  for (int rf = 0; rf < 2; ++rf)
#pragma unroll
    for (int r = 0; r < 4; ++r) {
      long row = row0 + rf * 16 + rbase + r;
      if (row < nrows) {
#pragma unroll
        for (int cf = 0; cf < NCF; ++cf) {
          int col = cf * 16 + lrow;
          if constexpr (OUT_BF16) {
            ((ushort*)Yv)[row * COLS + col] = f2bf(acc[rf][cf][r]);
          } else {
            ((float*)Yv)[row * COLS + col] = acc[rf][cf][r] + bias[col];
          }
        }
      }
    }
}

// ---------------- neighbor aggregation (one node per block) ----------------
// H bf16 [n][128]. 128 thr = 8 edge-groups x 16 lanes; uint4 (8 bf16) per lane.
// Output: bf16 hi/lo pair (feeds next MFMA GEMM). fp32 accumulate throughout.
__global__ __launch_bounds__(128) void agg_kernel(const ushort* __restrict__ H,
                                                  const int* __restrict__ row_off,
                                                  const int* __restrict__ edge_src,
                                                  const float* __restrict__ dinv,
                                                  const float* __restrict__ bias,
                                                  ushort* __restrict__ Ohi,
                                                  ushort* __restrict__ Olo, int n) {
  int i = blockIdx.x;
  int t = threadIdx.x;
  int g = t >> 4;        // edge group 0..7
  int c = t & 15;        // feature block: feats [8c, 8c+8)
  float di = dinv[i];
  int beg = row_off[i], end = row_off[i + 1];

  float acc[8];
#pragma unroll
  for (int k = 0; k < 8; ++k) acc[k] = 0.f;

  __shared__ int sidx[128];
  __shared__ float swt[128];
  for (int base = beg; base < end; base += 128) {
    int cnt = min(128, end - base);
    if (t < cnt) {
      int s = edge_src[base + t];
      sidx[t] = s;
      swt[t] = dinv[s] * di;
    }
    __syncthreads();
#pragma unroll 2
    for (int j = g; j < cnt; j += 8) {
      uint4 q = *(const uint4*)(H + (size_t)sidx[j] * 128 + c * 8);
      float w = swt[j];
      acc[0] = fmaf(bf_lo(q.x), w, acc[0]);
      acc[1] = fmaf(bf_hi(q.x), w, acc[1]);
      acc[2] = fmaf(bf_lo(q.y), w, acc[2]);
      acc[3] = fmaf(bf_hi(q.y), w, acc[3]);
      acc[4] = fmaf(bf_lo(q.z), w, acc[4]);
      acc[5] = fmaf(bf_hi(q.z), w, acc[5]);
      acc[6] = fmaf(bf_lo(q.w), w, acc[6]);
      acc[7] = fmaf(bf_hi(q.w), w, acc[7]);
    }
    __syncthreads();
  }

#pragma unroll
  for (int k = 0; k < 8; ++k) acc[k] += __shfl_down(acc[k], 32);
#pragma unroll
  for (int k = 0; k < 8; ++k) acc[k] += __shfl_down(acc[k], 16);

  __shared__ float red[16][8];
  if (t >= 64 && t < 80) {
#pragma unroll
    for (int k = 0; k < 8; ++k) red[c][k] = acc[k];
  }
  __syncthreads();
  if (t < 16) {
    uint4 q = *(const uint4*)(H + (size_t)i * 128 + c * 8);
    float sw = di * di;
    float self_[8] = {bf_lo(q.x), bf_hi(q.x), bf_lo(q.y), bf_hi(q.y),
                      bf_lo(q.z), bf_hi(q.z), bf_lo(q.w), bf_hi(q.w)};
    float4 bA = *(const float4*)(bias + c * 8);
    float4 bB = *(const float4*)(bias + c * 8 + 4);
    float o[8];
#pragma unroll
    for (int k = 0; k < 8; ++k) o[k] = acc[k] + red[c][k] + self_[k] * sw;
    o[0] += bA.x; o[1] += bA.y; o[2] += bA.z; o[3] += bA.w;
    o[4] += bB.x; o[5] += bB.y; o[6] += bB.z; o[7] += bB.w;
    ushort4 h0, h1, l0, l1;
#pragma unroll
    for (int k = 0; k < 8; ++k) o[k] = fmaxf(o[k], 0.f);
    split2(o[0], h0.x, l0.x); split2(o[1], h0.y, l0.y);
    split2(o[2], h0.z, l0.z); split2(o[3], h0.w, l0.w);
    split2(o[4], h1.x, l1.x); split2(o[5], h1.y, l1.y);
    split2(o[6], h1.z, l1.z); split2(o[7], h1.w, l1.w);
    *(ushort4*)(Ohi + (size_t)i * 128 + c * 8) = h0;
    *(ushort4*)(Ohi + (size_t)i * 128 + c * 8 + 4) = h1;
    *(ushort4*)(Olo + (size_t)i * 128 + c * 8) = l0;
    *(ushort4*)(Olo + (size_t)i * 128 + c * 8 + 4) = l1;
  }
}

// ---------------- host ----------------

extern "C" void kernel_launch(void* const* d_in, const int* in_sizes, int n_in,
                              void* d_out, int out_size, void* d_ws, size_t ws_size,
                              hipStream_t stream) {
  const float* x = (const float*)d_in[0];
  const int* ei = (const int*)d_in[1];
  const float* W1 = (const float*)d_in[2];
  const float* b1 = (const float*)d_in[3];
  const float* W2 = (const float*)d_in[4];
  const float* b2 = (const float*)d_in[5];
  const float* Wfc = (const float*)d_in[6];
  const float* bfc = (const float*)d_in[7];
  float* out = (float*)d_out;

  int N = in_sizes[0] / 128;
  int E = in_sizes[1] / 2;
  const int* srcp = ei;
  const int* dstp = ei + E;

  char* ws = (char*)d_ws;
  size_t off = 0;
  auto alloc = [&](size_t bytes) -> void* {
    void* p = ws + off;
    off += (bytes + 255) & ~(size_t)255;
    return p;
  };
  ushort* Hb = (ushort*)alloc((size_t)N * 128 * 2);    // bf16 post-GEMM features
  ushort* Xhi = (ushort*)alloc((size_t)N * 128 * 2);   // bf16 hi GEMM input
  ushort* Xlo = (ushort*)alloc((size_t)N * 128 * 2);   // bf16 lo GEMM input
  ushort* W1hiT = (ushort*)alloc(128 * 128 * 2);
  ushort* W1loT = (ushort*)alloc(128 * 128 * 2);
  ushort* W2hiT = (ushort*)alloc(128 * 128 * 2);
  ushort* W2loT = (ushort*)alloc(128 * 128 * 2);
  ushort* WfhiT = (ushort*)alloc(128 * 64 * 2);
  ushort* WfloT = (ushort*)alloc(128 * 64 * 2);
  int* deg = (int*)alloc((size_t)N * 4);
  int* row_off = (int*)alloc((size_t)(N + 1) * 4);
  int* cursor = (int*)alloc((size_t)N * 4);
  int* blocksums = (int*)alloc(512 * 4);
  float* dinv = (float*)alloc((size_t)N * 4);
  int* edge_src = (int*)alloc((size_t)E * 4);

  hipMemsetAsync(deg, 0, (size_t)N * 4, stream);
  hipMemsetAsync(cursor, 0, (size_t)N * 4, stream);

  // input splits (independent of CSR build)
  split_x_kernel<<<2048, 256, 0, stream>>>(x, Xhi, Xlo, N * 32);
  split_wT_kernel<<<(128 * 128 + 255) / 256, 256, 0, stream>>>(W1, W1hiT, W1loT, 128);
  split_wT_kernel<<<(128 * 128 + 255) / 256, 256, 0, stream>>>(W2, W2hiT, W2loT, 128);
  split_wT_kernel<<<(128 * 64 + 255) / 256, 256, 0, stream>>>(Wfc, WfhiT, WfloT, 64);

  int nbE = (E + 255) / 256;
  if (nbE > 2048) nbE = 2048;
  hist_kernel<<<nbE, 256, 0, stream>>>(dstp, deg, E);

  int nbScan = (N + 255) / 256;  // 391 for N=100000, fits scan2's 512 threads
  scan1<<<nbScan, 256, 0, stream>>>(deg, row_off, blocksums, N);
  scan2<<<1, 512, 0, stream>>>(blocksums, nbScan, row_off + N);
  scan3_dinv<<<nbScan, 256, 0, stream>>>(row_off, blocksums, deg, dinv, N);

  constexpr int NPASS = 4;
  int wsz = (N + NPASS - 1) / NPASS;
  for (int w = 0; w < NPASS; ++w) {
    int lo = w * wsz;
    int hi = min(N, lo + wsz);
    scatter_kernel<<<nbE, 256, 0, stream>>>(srcp, dstp, row_off, cursor, edge_src, E, lo, hi);
  }

  int nbG = (N + 127) / 128;
  // layer 1
  gemm_mfma<128, true><<<nbG, 256, 0, stream>>>(Xhi, Xlo, W1hiT, W1loT, nullptr, Hb, N);
  agg_kernel<<<N, 128, 0, stream>>>(Hb, row_off, edge_src, dinv, b1, Xhi, Xlo, N);
  // layer 2
  gemm_mfma<128, true><<<nbG, 256, 0, stream>>>(Xhi, Xlo, W2hiT, W2loT, nullptr, Hb, N);
  agg_kernel<<<N, 128, 0, stream>>>(Hb, row_off, edge_src, dinv, b2, Xhi, Xlo, N);
  // final FC
  gemm_mfma<64, false><<<nbG, 256, 0, stream>>>(Xhi, Xlo, WfhiT, WfloT, bfc, out, N);
}

// Round 8
// 544.936 us; speedup vs baseline: 1.0449x; 1.0449x over previous
//
#include <hip/hip_runtime.h>

typedef unsigned int uint;
typedef unsigned short ushort;

typedef short bf16x8 __attribute__((ext_vector_type(8)));
typedef float f32x4 __attribute__((ext_vector_type(4)));

__device__ inline ushort f2bf(float f) {
  uint u = __float_as_uint(f);
  u += 0x7fffu + ((u >> 16) & 1u);   // round-to-nearest-even
  return (ushort)(u >> 16);
}
__device__ inline float bf2f(ushort h) { return __uint_as_float((uint)h << 16); }
__device__ inline float bf_lo(uint u) { return __uint_as_float(u << 16); }
__device__ inline float bf_hi(uint u) { return __uint_as_float(u & 0xffff0000u); }
__device__ inline void split2(float v, ushort& h, ushort& l) {
  ushort hh = f2bf(v);
  h = hh;
  l = f2bf(v - bf2f(hh));    // exact residual, captures ~8 more mantissa bits
}

// ---------------- CSR construction ----------------

__global__ __launch_bounds__(256) void hist_kernel(const int* __restrict__ dst,
                                                   int* __restrict__ deg, int nE) {
  int i = blockIdx.x * 256 + threadIdx.x;
  int stride = gridDim.x * 256;
  for (; i < nE; i += stride) atomicAdd(&deg[dst[i]], 1);
}

__global__ __launch_bounds__(256) void scan1(const int* __restrict__ deg,
                                             int* __restrict__ row_off,
                                             int* __restrict__ blocksums, int n) {
  __shared__ int s[256];
  int t = threadIdx.x, i = blockIdx.x * 256 + t;
  int v = (i < n) ? deg[i] : 0;
  s[t] = v;
  __syncthreads();
  for (int off = 1; off < 256; off <<= 1) {
    int x = (t >= off) ? s[t - off] : 0;
    __syncthreads();
    s[t] += x;
    __syncthreads();
  }
  if (i < n) row_off[i] = s[t] - v;        // local exclusive scan
  if (t == 255) blocksums[blockIdx.x] = s[t];
}

__global__ __launch_bounds__(512) void scan2(int* __restrict__ blocksums, int nb,
                                             int* __restrict__ total_out) {
  __shared__ int s[512];
  int t = threadIdx.x;
  int v = (t < nb) ? blocksums[t] : 0;
  s[t] = v;
  __syncthreads();
  for (int off = 1; off < 512; off <<= 1) {
    int x = (t >= off) ? s[t - off] : 0;
    __syncthreads();
    s[t] += x;
    __syncthreads();
  }
  if (t < nb) blocksums[t] = s[t] - v;     // exclusive block offsets
  if (t == 511) *total_out = s[511];       // row_off[N] = nE
}

__global__ __launch_bounds__(256) void scan3_dinv(int* __restrict__ row_off,
                                                  const int* __restrict__ blockoff,
                                                  const int* __restrict__ deg,
                                                  float* __restrict__ dinv, int n) {
  int i = blockIdx.x * 256 + threadIdx.x;
  if (i < n) {
    row_off[i] += blockoff[i >> 8];
    dinv[i] = rsqrtf((float)deg[i] + 1.0f);
  }
}

// Windowed counting-sort scatter (4 passes): write span per pass is contiguous
// ~1.6 MB -> L2-resident, lines fill fully before eviction.
__global__ __launch_bounds__(256) void scatter_kernel(const int* __restrict__ src,
                                                      const int* __restrict__ dst,
                                                      const int* __restrict__ row_off,
                                                      int* __restrict__ cursor,
                                                      int* __restrict__ edge_src, int nE,
                                                      int lo, int hi) {
  int i = blockIdx.x * 256 + threadIdx.x;
  int stride = gridDim.x * 256;
  for (; i < nE; i += stride) {
    int d = dst[i];
    if (d >= lo && d < hi) {
      int pos = row_off[d] + atomicAdd(&cursor[d], 1);
      edge_src[pos] = src[i];
    }
  }
}

// ---------------- input splitting (fp32 -> bf16 hi/lo pair) ----------------

__global__ __launch_bounds__(256) void split_x_kernel(const float* __restrict__ X,
                                                      ushort* __restrict__ Xhi,
                                                      ushort* __restrict__ Xlo, int n4) {
  int i = blockIdx.x * 256 + threadIdx.x;
  int stride = gridDim.x * 256;
  for (; i < n4; i += stride) {
    float4 v = *(const float4*)(X + (size_t)i * 4);
    ushort4 h, l;
    split2(v.x, h.x, l.x);
    split2(v.y, h.y, l.y);
    split2(v.z, h.z, l.z);
    split2(v.w, h.w, l.w);
    *(ushort4*)(Xhi + (size_t)i * 4) = h;
    *(ushort4*)(Xlo + (size_t)i * 4) = l;
  }
}

// W [K=128][C] row-major -> transposed hi/lo [C][128]
__global__ __launch_bounds__(256) void split_wT_kernel(const float* __restrict__ W,
                                                       ushort* __restrict__ WThi,
                                                       ushort* __restrict__ WTlo, int C) {
  int idx = blockIdx.x * 256 + threadIdx.x;
  if (idx < 128 * C) {
    int k = idx / C, c = idx % C;
    ushort h, l;
    split2(W[idx], h, l);
    WThi[c * 128 + k] = h;
    WTlo[c * 128 + k] = l;
  }
}

// ---------------- MFMA GEMM: Y[N][COLS] = X[N][128] @ W[128][COLS] ----------------
// bf16 hi/lo split inputs; product = hi*hi + hi*lo + lo*hi (~2^-18 rel error).
// 256 thr = 4 waves; block tile 128 rows; wave tile 32 rows (2 rf).
// Per ks-step (K=32 slice): stage W-slice hi+lo into LDS (80 B row stride ->
// bank stride 20, 2-way max = free), then ds_read_b128 B-frags + MFMA.
// ks-loop NOT unrolled: bounds in-flight loads (~130 VGPR, no spill).
template <int COLS, bool OUT_BF16>
__global__ __launch_bounds__(256) void gemm_mfma(const ushort* __restrict__ Ahi,
                                                 const ushort* __restrict__ Alo,
                                                 const ushort* __restrict__ WThi,
                                                 const ushort* __restrict__ WTlo,
                                                 const float* __restrict__ bias,
                                                 void* __restrict__ Yv, int nrows) {
  constexpr int NCF = COLS / 16;       // col fragments: 8 or 4
  constexpr int NH = COLS * 4 / 256;   // 16B-chunks per thread per half (2 or 1)
  __shared__ __align__(16) ushort Bs[2][COLS][40];   // [hi/lo][col][32k + pad]

  int tid = threadIdx.x;
  int w = tid >> 6;
  int lane = tid & 63;
  int lrow = lane & 15;
  int q = lane >> 4;                   // k-quarter 0..3
  long row0 = (long)blockIdx.x * 128 + w * 32;

  f32x4 acc[2][NCF];
#pragma unroll
  for (int rf = 0; rf < 2; ++rf)
#pragma unroll
    for (int cf = 0; cf < NCF; ++cf) acc[rf][cf] = (f32x4){0.f, 0.f, 0.f, 0.f};

  const bf16x8 zero8 = {0, 0, 0, 0, 0, 0, 0, 0};

#pragma unroll 1
  for (int ks = 0; ks < 4; ++ks) {
    int kk = ks * 32 + q * 8;
    // A fragments direct to registers (each element used once)
    bf16x8 a_hi[2], a_lo[2];
#pragma unroll
    for (int rf = 0; rf < 2; ++rf) {
      long r = row0 + rf * 16 + lrow;
      bool ok = r < nrows;
      a_hi[rf] = ok ? *(const bf16x8*)(Ahi + r * 128 + kk) : zero8;
      a_lo[rf] = ok ? *(const bf16x8*)(Alo + r * 128 + kk) : zero8;
    }
    // stage W-slice [COLS][32k] hi+lo into LDS via registers
    uint4 th[NH], tl[NH];
#pragma unroll
    for (int j = 0; j < NH; ++j) {
      int ci = j * 256 + tid;          // chunk id: c = ci>>2, qc = ci&3
      int c = ci >> 2, qc = ci & 3;
      th[j] = *(const uint4*)(WThi + c * 128 + ks * 32 + qc * 8);
      tl[j] = *(const uint4*)(WTlo + c * 128 + ks * 32 + qc * 8);
    }
    __syncthreads();   // previous iteration's reads done before overwrite
#pragma unroll
    for (int j = 0; j < NH; ++j) {
      int ci = j * 256 + tid;
      int c = ci >> 2, qc = ci & 3;
      *(uint4*)(&Bs[0][c][qc * 8]) = th[j];
      *(uint4*)(&Bs[1][c][qc * 8]) = tl[j];
    }
    __syncthreads();
    // compute: per col-fragment, ds_read B hi/lo then 6 MFMA
#pragma unroll
    for (int cf = 0; cf < NCF; ++cf) {
      bf16x8 b_hi = *(const bf16x8*)(&Bs[0][cf * 16 + lrow][q * 8]);
      bf16x8 b_lo = *(const bf16x8*)(&Bs[1][cf * 16 + lrow][q * 8]);
#pragma unroll
      for (int rf = 0; rf < 2; ++rf) {
        acc[rf][cf] = __builtin_amdgcn_mfma_f32_16x16x32_bf16(a_hi[rf], b_hi, acc[rf][cf], 0, 0, 0);
        acc[rf][cf] = __builtin_amdgcn_mfma_f32_16x16x32_bf16(a_hi[rf], b_lo, acc[rf][cf], 0, 0, 0);
        acc[rf][cf] = __builtin_amdgcn_mfma_f32_16x16x32_bf16(a_lo[rf], b_hi, acc[rf][cf], 0, 0, 0);
      }
    }
  }

  // epilogue: C/D layout col=lane&15, row=(lane>>4)*4+r  [m89-verified]
  int rbase = q * 4;
#pragma unroll
  for (int rf = 0; rf < 2; ++rf)
#pragma unroll
    for (int r = 0; r < 4; ++r) {
      long row = row0 + rf * 16 + rbase + r;
      if (row < nrows) {
#pragma unroll
        for (int cf = 0; cf < NCF; ++cf) {
          int col = cf * 16 + lrow;
          if constexpr (OUT_BF16) {
            ((ushort*)Yv)[row * COLS + col] = f2bf(acc[rf][cf][r]);
          } else {
            ((float*)Yv)[row * COLS + col] = acc[rf][cf][r] + bias[col];
          }
        }
      }
    }
}

// ---------------- neighbor aggregation (one node per block) ----------------
// H bf16 [n][128]. 128 thr = 8 edge-groups x 16 lanes; uint4 (8 bf16) per lane.
// Output: bf16 hi/lo pair (feeds next MFMA GEMM). fp32 accumulate throughout.
__global__ __launch_bounds__(128) void agg_kernel(const ushort* __restrict__ H,
                                                  const int* __restrict__ row_off,
                                                  const int* __restrict__ edge_src,
                                                  const float* __restrict__ dinv,
                                                  const float* __restrict__ bias,
                                                  ushort* __restrict__ Ohi,
                                                  ushort* __restrict__ Olo, int n) {
  int i = blockIdx.x;
  int t = threadIdx.x;
  int g = t >> 4;        // edge group 0..7
  int c = t & 15;        // feature block: feats [8c, 8c+8)
  float di = dinv[i];
  int beg = row_off[i], end = row_off[i + 1];

  float acc[8];
#pragma unroll
  for (int k = 0; k < 8; ++k) acc[k] = 0.f;

  __shared__ int sidx[128];
  __shared__ float swt[128];
  for (int base = beg; base < end; base += 128) {
    int cnt = min(128, end - base);
    if (t < cnt) {
      int s = edge_src[base + t];
      sidx[t] = s;
      swt[t] = dinv[s] * di;
    }
    __syncthreads();
#pragma unroll 2
    for (int j = g; j < cnt; j += 8) {
      uint4 qv = *(const uint4*)(H + (size_t)sidx[j] * 128 + c * 8);
      float w = swt[j];
      acc[0] = fmaf(bf_lo(qv.x), w, acc[0]);
      acc[1] = fmaf(bf_hi(qv.x), w, acc[1]);
      acc[2] = fmaf(bf_lo(qv.y), w, acc[2]);
      acc[3] = fmaf(bf_hi(qv.y), w, acc[3]);
      acc[4] = fmaf(bf_lo(qv.z), w, acc[4]);
      acc[5] = fmaf(bf_hi(qv.z), w, acc[5]);
      acc[6] = fmaf(bf_lo(qv.w), w, acc[6]);
      acc[7] = fmaf(bf_hi(qv.w), w, acc[7]);
    }
    __syncthreads();
  }

#pragma unroll
  for (int k = 0; k < 8; ++k) acc[k] += __shfl_down(acc[k], 32);
#pragma unroll
  for (int k = 0; k < 8; ++k) acc[k] += __shfl_down(acc[k], 16);

  __shared__ float red[16][8];
  if (t >= 64 && t < 80) {
#pragma unroll
    for (int k = 0; k < 8; ++k) red[c][k] = acc[k];
  }
  __syncthreads();
  if (t < 16) {
    uint4 qv = *(const uint4*)(H + (size_t)i * 128 + c * 8);
    float sw = di * di;
    float self_[8] = {bf_lo(qv.x), bf_hi(qv.x), bf_lo(qv.y), bf_hi(qv.y),
                      bf_lo(qv.z), bf_hi(qv.z), bf_lo(qv.w), bf_hi(qv.w)};
    float4 bA = *(const float4*)(bias + c * 8);
    float4 bB = *(const float4*)(bias + c * 8 + 4);
    float o[8];
#pragma unroll
    for (int k = 0; k < 8; ++k) o[k] = acc[k] + red[c][k] + self_[k] * sw;
    o[0] += bA.x; o[1] += bA.y; o[2] += bA.z; o[3] += bA.w;
    o[4] += bB.x; o[5] += bB.y; o[6] += bB.z; o[7] += bB.w;
    ushort4 h0, h1, l0, l1;
#pragma unroll
    for (int k = 0; k < 8; ++k) o[k] = fmaxf(o[k], 0.f);
    split2(o[0], h0.x, l0.x); split2(o[1], h0.y, l0.y);
    split2(o[2], h0.z, l0.z); split2(o[3], h0.w, l0.w);
    split2(o[4], h1.x, l1.x); split2(o[5], h1.y, l1.y);
    split2(o[6], h1.z, l1.z); split2(o[7], h1.w, l1.w);
    *(ushort4*)(Ohi + (size_t)i * 128 + c * 8) = h0;
    *(ushort4*)(Ohi + (size_t)i * 128 + c * 8 + 4) = h1;
    *(ushort4*)(Olo + (size_t)i * 128 + c * 8) = l0;
    *(ushort4*)(Olo + (size_t)i * 128 + c * 8 + 4) = l1;
  }
}

// ---------------- host ----------------

extern "C" void kernel_launch(void* const* d_in, const int* in_sizes, int n_in,
                              void* d_out, int out_size, void* d_ws, size_t ws_size,
                              hipStream_t stream) {
  const float* x = (const float*)d_in[0];
  const int* ei = (const int*)d_in[1];
  const float* W1 = (const float*)d_in[2];
  const float* b1 = (const float*)d_in[3];
  const float* W2 = (const float*)d_in[4];
  const float* b2 = (const float*)d_in[5];
  const float* Wfc = (const float*)d_in[6];
  const float* bfc = (const float*)d_in[7];
  float* out = (float*)d_out;

  int N = in_sizes[0] / 128;
  int E = in_sizes[1] / 2;
  const int* srcp = ei;
  const int* dstp = ei + E;

  char* ws = (char*)d_ws;
  size_t off = 0;
  auto alloc = [&](size_t bytes) -> void* {
    void* p = ws + off;
    off += (bytes + 255) & ~(size_t)255;
    return p;
  };
  ushort* Hb = (ushort*)alloc((size_t)N * 128 * 2);    // bf16 post-GEMM features
  ushort* Xhi = (ushort*)alloc((size_t)N * 128 * 2);   // bf16 hi GEMM input
  ushort* Xlo = (ushort*)alloc((size_t)N * 128 * 2);   // bf16 lo GEMM input
  ushort* W1hiT = (ushort*)alloc(128 * 128 * 2);
  ushort* W1loT = (ushort*)alloc(128 * 128 * 2);
  ushort* W2hiT = (ushort*)alloc(128 * 128 * 2);
  ushort* W2loT = (ushort*)alloc(128 * 128 * 2);
  ushort* WfhiT = (ushort*)alloc(128 * 64 * 2);
  ushort* WfloT = (ushort*)alloc(128 * 64 * 2);
  int* deg = (int*)alloc((size_t)N * 4);
  int* row_off = (int*)alloc((size_t)(N + 1) * 4);
  int* cursor = (int*)alloc((size_t)N * 4);
  int* blocksums = (int*)alloc(512 * 4);
  float* dinv = (float*)alloc((size_t)N * 4);
  int* edge_src = (int*)alloc((size_t)E * 4);

  hipMemsetAsync(deg, 0, (size_t)N * 4, stream);
  hipMemsetAsync(cursor, 0, (size_t)N * 4, stream);

  // input splits (independent of CSR build)
  split_x_kernel<<<2048, 256, 0, stream>>>(x, Xhi, Xlo, N * 32);
  split_wT_kernel<<<(128 * 128 + 255) / 256, 256, 0, stream>>>(W1, W1hiT, W1loT, 128);
  split_wT_kernel<<<(128 * 128 + 255) / 256, 256, 0, stream>>>(W2, W2hiT, W2loT, 128);
  split_wT_kernel<<<(128 * 64 + 255) / 256, 256, 0, stream>>>(Wfc, WfhiT, WfloT, 64);

  int nbE = (E + 255) / 256;
  if (nbE > 2048) nbE = 2048;
  hist_kernel<<<nbE, 256, 0, stream>>>(dstp, deg, E);

  int nbScan = (N + 255) / 256;  // 391 for N=100000, fits scan2's 512 threads
  scan1<<<nbScan, 256, 0, stream>>>(deg, row_off, blocksums, N);
  scan2<<<1, 512, 0, stream>>>(blocksums, nbScan, row_off + N);
  scan3_dinv<<<nbScan, 256, 0, stream>>>(row_off, blocksums, deg, dinv, N);

  constexpr int NPASS = 4;
  int wsz = (N + NPASS - 1) / NPASS;
  for (int w = 0; w < NPASS; ++w) {
    int lo = w * wsz;
    int hi = min(N, lo + wsz);
    scatter_kernel<<<nbE, 256, 0, stream>>>(srcp, dstp, row_off, cursor, edge_src, E, lo, hi);
  }

  int nbG = (N + 127) / 128;
  // layer 1
  gemm_mfma<128, true><<<nbG, 256, 0, stream>>>(Xhi, Xlo, W1hiT, W1loT, nullptr, Hb, N);
  agg_kernel<<<N, 128, 0, stream>>>(Hb, row_off, edge_src, dinv, b1, Xhi, Xlo, N);
  // layer 2
  gemm_mfma<128, true><<<nbG, 256, 0, stream>>>(Xhi, Xlo, W2hiT, W2loT, nullptr, Hb, N);
  agg_kernel<<<N, 128, 0, stream>>>(Hb, row_off, edge_src, dinv, b2, Xhi, Xlo, N);
  // final FC
  gemm_mfma<64, false><<<nbG, 256, 0, stream>>>(Xhi, Xlo, WfhiT, WfloT, bfc, out, N);
}